// Round 3
// baseline (3770.574 us; speedup 1.0000x reference)
//
#include <hip/hip_runtime.h>
#include <stdint.h>

typedef unsigned short u16;
typedef __bf16 bf16x8 __attribute__((ext_vector_type(8)));
typedef float floatx4 __attribute__((ext_vector_type(4)));

#define N_OBJ    131072
#define L0R      262144
#define L1R      524288
#define L2R      393216
#define TOTI     (L0R + L1R + L2R)   // 1179648

// ---- workspace layout (bytes), total ~55.5 MB ----
// s      fp32 [64][N] col-major   @ 0          (33,554,432)
// wt     bf16 transposed weights  @ 33554432   (278,528)
// flag   u8   [N] written-by-rel0 @ 33832960   (131,072)
// maxmsg bf16 [N][64]             @ 33964032   (16,777,216)
// nidx   i32  [TOTI] normalized   @ 50741248   (4,718,592)

__device__ __forceinline__ float bf2f(u16 u) {
  union { uint32_t i; float f; } v; v.i = ((uint32_t)u) << 16; return v.f;
}
__device__ __forceinline__ u16 f2bf(float f) {
  union { float f; uint32_t i; } v; v.f = f;
  uint32_t r = (v.i + 0x7FFFu + ((v.i >> 16) & 1u)) >> 16;
  return (u16)r;
}
__device__ __forceinline__ uint4 pack8(const float* sp) {
  float4 f0 = *(const float4*)(sp);
  float4 f1 = *(const float4*)(sp + 4);
  uint4 v;
  v.x = (uint32_t)f2bf(f0.x) | ((uint32_t)f2bf(f0.y) << 16);
  v.y = (uint32_t)f2bf(f0.z) | ((uint32_t)f2bf(f0.w) << 16);
  v.z = (uint32_t)f2bf(f1.x) | ((uint32_t)f2bf(f1.y) << 16);
  v.w = (uint32_t)f2bf(f1.z) | ((uint32_t)f2bf(f1.w) << 16);
  return v;
}
// mish(x) = x*tanh(softplus(x)) = x*((1+e^x)^2-1)/((1+e^x)^2+1)
__device__ __forceinline__ float mish_f(float x) {
  float t = __expf(fminf(x, 30.f));
  float u = 1.f + t; u = u * u;
  return x * (u - 1.f) / (u + 1.f);
}

// ---------- normalize indices: auto-detect int64 vs int32, emit int32 ----------
__global__ __launch_bounds__(256) void norm_kernel(
    const int* __restrict__ r0, const int* __restrict__ r1,
    const int* __restrict__ r2, int* __restrict__ n)
{
  int g = blockIdx.x * 256 + (int)threadIdx.x;   // grid covers TOTI exactly
  const int* src; int off;
  if (g < L0R)              { src = r0; off = g; }
  else if (g < L0R + L1R)   { src = r1; off = g - L0R; }
  else                      { src = r2; off = g - L0R - L1R; }
  // wave-uniform probe: odd 32-bit words of first 64 elements all zero <=> int64
  int lane = (int)threadIdx.x & 63;
  int probe = src[2 * lane + 1];
  bool i64 = (__ballot(probe == 0) == ~0ull);
  n[g] = i64 ? src[2 * off] : src[off];
}

// ---------- prep: fp32 weights -> bf16 W^T ----------
__global__ __launch_bounds__(256) void prep_kernel(
    const float* w0, const float* w1, const float* w2, const float* w3,
    const float* w4, const float* w5, const float* w6, const float* w7,
    u16* __restrict__ wt)
{
  int b = blockIdx.x;
  const float* srcs[8] = {w0, w1, w2, w3, w4, w5, w6, w7};
  const int fi[8]   = {64, 64, 128, 128, 192, 192, 128, 128};
  const int fo[8]   = {64, 64, 128, 128, 192, 192, 128, 64};
  const int boff[9] = {0, 16, 32, 96, 160, 304, 448, 512, 544};
  const int woff[8] = {0, 4096, 8192, 24576, 40960, 77824, 114688, 131072};
  int m = 0;
  #pragma unroll
  for (int j = 0; j < 8; ++j) if (b >= boff[j + 1]) m = j + 1;
  int e = (b - boff[m]) * 256 + (int)threadIdx.x;
  int k = e / fo[m];
  int n = e - k * fo[m];
  wt[woff[m] + n * fi[m] + k] = f2bf(srcs[m][e]);   // wt row n: K-contiguous
}

// ---------- flag objects written by relation 0 ----------
__global__ __launch_bounds__(256) void flag_kernel(
    const int* __restrict__ idx0, unsigned char* __restrict__ flag)
{
  int g = blockIdx.x * 256 + (int)threadIdx.x;   // covers L0R exactly
  flag[idx0[g]] = 1;
}

// ---------- matmul phase: acc[NTOUT tiles] = A(g_lds) * W^T ----------
template<int D, int NTOUT>
__device__ __forceinline__ void matmul_phase(
    const u16* __restrict__ wtsrc, u16* w_lds,
    const bf16x8 (&af)[D / 32], floatx4 (&acc)[D / 16],
    int tid, int q, int i)
{
  constexpr int PITCH = D + 8;
  #pragma unroll
  for (int t = 0; t < NTOUT; ++t) acc[t] = (floatx4)0.f;
  #pragma unroll
  for (int ch = 0; ch < NTOUT / 4; ++ch) {
    __syncthreads();   // protect w_lds against previous readers
    for (int c = tid; c < 64 * (D / 8); c += 256) {
      int nr = c / (D / 8), p = c - nr * (D / 8);
      *(uint4*)(&w_lds[nr * PITCH + p * 8]) =
          *(const uint4*)(wtsrc + (size_t)(ch * 64 + nr) * D + p * 8);
    }
    __syncthreads();
    #pragma unroll
    for (int k = 0; k < D / 32; ++k) {
      #pragma unroll
      for (int nt = 0; nt < 4; ++nt) {
        bf16x8 bf = *(const bf16x8*)(&w_lds[(nt * 16 + i) * PITCH + k * 32 + q * 8]);
        acc[ch * 4 + nt] =
            __builtin_amdgcn_mfma_f32_16x16x32_bf16(af[k], bf, acc[ch * 4 + nt], 0, 0, 0);
      }
    }
  }
}

// ---------- fused gather + 2-layer MLP ----------
// MODE 0: relation kernel; rows gathered via idx from fp32 obj_emb; epilogue
//         scatters atomicAdd(exp(12*y)) into s[col][obj] (col-major fp32).
// MODE 1: update kernel; rows = [maxmsg(bf16) | obj_emb(fp32)] -> fp32 d_out.
template<int D, int DOUT, int MODE>
__global__ __launch_bounds__(256, (D >= 192) ? 3 : 4) void mlp_kernel(
    const float* __restrict__ srcE, const u16* __restrict__ srcM,
    const int* __restrict__ idx,
    const u16* __restrict__ rwt, const float* __restrict__ rb,
    const u16* __restrict__ owt, const float* __restrict__ ob,
    float* __restrict__ dstF, float* __restrict__ dstS)
{
  constexpr int A = D / 64;
  constexpr int PITCH = D + 8;   // bf16 elems; rows 16B aligned
  constexpr int NT1 = D / 16;
  constexpr int NT2 = DOUT / 16;
  constexpr int KI = D / 32;
  __shared__ alignas(16) u16 g_lds[64 * PITCH];
  __shared__ alignas(16) u16 w_lds[64 * PITCH];
  __shared__ float b1_lds[D];
  __shared__ float b2_lds[DOUT];
  __shared__ int i_lds[64 * A];

  const int tid = threadIdx.x;
  const int wave = tid >> 6;
  const int lane = tid & 63;
  const int q = lane >> 4;
  const int i = lane & 15;
  const int t0 = blockIdx.x * 64;

  for (int c = tid; c < D; c += 256) b1_lds[c] = rb[c];
  for (int c = tid; c < DOUT; c += 256) b2_lds[c] = ob[c];
  if (MODE == 0 && tid < 64 * A) i_lds[tid] = idx[t0 * A + tid];

  // stage G: 64 tuples x A entity-rows x 8 chunks of 8 bf16 (fp32 -> bf16)
  for (int c = tid; c < 64 * A * 8; c += 256) {
    int e = c >> 3, p = c & 7;
    int r = e / A, sl = e - r * A;
    uint4 val;
    if (MODE == 0) {
      int obj = idx[(t0 + r) * A + sl];
      val = pack8(srcE + (size_t)obj * 64 + p * 8);
    } else {
      if (sl == 0) val = *(const uint4*)(srcM + (size_t)(t0 + r) * 64 + p * 8);
      else         val = pack8(srcE + (size_t)(t0 + r) * 64 + p * 8);
    }
    *(uint4*)(&g_lds[r * PITCH + sl * 64 + p * 8]) = val;
  }
  __syncthreads();

  floatx4 acc[NT1];
  bf16x8 af[KI];

  // phase 1: H = G @ RW
  #pragma unroll
  for (int k = 0; k < KI; ++k)
    af[k] = *(const bf16x8*)(&g_lds[(wave * 16 + i) * PITCH + k * 32 + q * 8]);
  matmul_phase<D, NT1>(rwt, w_lds, af, acc, tid, q, i);

  // epilogue 1: a2 = g + mish(h) in place (each wave owns its 16 rows)
  #pragma unroll
  for (int t = 0; t < NT1; ++t) {
    #pragma unroll
    for (int r = 0; r < 4; ++r) {
      int row = wave * 16 + q * 4 + r;
      int col = t * 16 + i;
      float h = acc[t][r] + b1_lds[col];
      float g = bf2f(g_lds[row * PITCH + col]);
      g_lds[row * PITCH + col] = f2bf(g + mish_f(h));
    }
  }

  // phase 2: Y = A2 @ OW
  #pragma unroll
  for (int k = 0; k < KI; ++k)
    af[k] = *(const bf16x8*)(&g_lds[(wave * 16 + i) * PITCH + k * 32 + q * 8]);
  matmul_phase<D, NT2>(owt, w_lds, af, acc, tid, q, i);

  // epilogue 2
  #pragma unroll
  for (int t = 0; t < NT2; ++t) {
    #pragma unroll
    for (int r = 0; r < 4; ++r) {
      int row = wave * 16 + q * 4 + r;
      int col = t * 16 + i;
      float y = acc[t][r] + b2_lds[col];
      if (MODE == 0) {
        int slot = col >> 6, cc = col & 63;
        int obj = i_lds[row * A + slot];
        atomicAdd(&dstS[(size_t)cc * N_OBJ + obj], __expf(fminf(12.f * y, 82.f)));
      } else {
        dstF[(size_t)(t0 + row) * 64 + col] = y;
      }
    }
  }
}

// ---------- finalize: maxmsg[o][c] = log(s[c][o] + eps)/12 (bf16 into ws) ----------
__global__ __launch_bounds__(256) void final_kernel(
    const float* __restrict__ s, const unsigned char* __restrict__ flag,
    u16* __restrict__ maxmsg)
{
  __shared__ alignas(16) u16 t_lds[64 * 72];
  int tid = (int)threadIdx.x;
  int o0 = blockIdx.x * 64;
  int ol = tid & 63;
  int o = o0 + ol;
  float add = flag[o] ? 1e-37f : 1e-16f;
  for (int c4 = 0; c4 < 64; c4 += 4) {
    int c = c4 + (tid >> 6);
    float v = s[(size_t)c * N_OBJ + o];
    t_lds[ol * 72 + c] = f2bf(__logf(v + add) * (1.f / 12.f));
  }
  __syncthreads();
  for (int cc = tid; cc < 512; cc += 256) {
    int r = cc >> 3, p = cc & 7;
    *(uint4*)(&maxmsg[(size_t)(o0 + r) * 64 + p * 8]) = *(uint4*)(&t_lds[r * 72 + p * 8]);
  }
}

extern "C" void kernel_launch(void* const* d_in, const int* in_sizes, int n_in,
                              void* d_out, int out_size, void* d_ws, size_t ws_size,
                              hipStream_t stream)
{
  (void)in_sizes; (void)n_in; (void)out_size; (void)ws_size;
  const float* obj_emb = (const float*)d_in[0];
  const float* r0rb = (const float*)d_in[5];
  const float* r0ob = (const float*)d_in[7];
  const float* r1rb = (const float*)d_in[9];
  const float* r1ob = (const float*)d_in[11];
  const float* r2rb = (const float*)d_in[13];
  const float* r2ob = (const float*)d_in[15];
  const float* urb  = (const float*)d_in[17];
  const float* uob  = (const float*)d_in[19];

  char* ws = (char*)d_ws;
  float* s           = (float*)(ws);
  u16* wt            = (u16*)(ws + 33554432ull);
  unsigned char* flg = (unsigned char*)(ws + 33832960ull);
  u16* maxmsg        = (u16*)(ws + 33964032ull);
  int* nidx          = (int*)(ws + 50741248ull);
  float* out         = (float*)d_out;

  hipMemsetAsync(s, 0, 64ull * N_OBJ * 4ull, stream);
  hipMemsetAsync(flg, 0, N_OBJ, stream);

  norm_kernel<<<TOTI / 256, 256, 0, stream>>>(
      (const int*)d_in[1], (const int*)d_in[2], (const int*)d_in[3], nidx);
  prep_kernel<<<544, 256, 0, stream>>>(
      (const float*)d_in[4], (const float*)d_in[6], (const float*)d_in[8],
      (const float*)d_in[10], (const float*)d_in[12], (const float*)d_in[14],
      (const float*)d_in[16], (const float*)d_in[18], wt);
  flag_kernel<<<L0R / 256, 256, 0, stream>>>(nidx, flg);

  mlp_kernel<64, 64, 0><<<4096, 256, 0, stream>>>(
      obj_emb, nullptr, nidx, wt + 0, r0rb, wt + 4096, r0ob, nullptr, s);
  mlp_kernel<128, 128, 0><<<4096, 256, 0, stream>>>(
      obj_emb, nullptr, nidx + L0R, wt + 8192, r1rb, wt + 24576, r1ob, nullptr, s);
  mlp_kernel<192, 192, 0><<<2048, 256, 0, stream>>>(
      obj_emb, nullptr, nidx + L0R + L1R, wt + 40960, r2rb, wt + 77824, r2ob, nullptr, s);

  final_kernel<<<N_OBJ / 64, 256, 0, stream>>>(s, flg, maxmsg);

  mlp_kernel<128, 64, 1><<<2048, 256, 0, stream>>>(
      obj_emb, maxmsg, nullptr, wt + 114688, urb, wt + 131072, uob, out, nullptr);
}

// Round 4
// 482.384 us; speedup vs baseline: 7.8165x; 7.8165x over previous
//
#include <hip/hip_runtime.h>
#include <stdint.h>

typedef unsigned short u16;
typedef __bf16 bf16x8 __attribute__((ext_vector_type(8)));
typedef float floatx4 __attribute__((ext_vector_type(4)));

#define N_OBJ    131072
#define L0R      262144
#define L1R      524288
#define L2R      393216
#define TOTI     (L0R + L1R + L2R)   // 1179648

// ---- workspace layout (bytes), total ~55.5 MB ----
// s      fp32 [N][64] ROW-major   @ 0          (33,554,432)
// wt     bf16 transposed weights  @ 33554432   (278,528)
// flag   u8   [N] written-by-rel0 @ 33832960   (131,072)
// maxmsg bf16 [N][64]             @ 33964032   (16,777,216)
// nidx   i32  [TOTI] normalized   @ 50741248   (4,718,592)

__device__ __forceinline__ float bf2f(u16 u) {
  union { uint32_t i; float f; } v; v.i = ((uint32_t)u) << 16; return v.f;
}
__device__ __forceinline__ u16 f2bf(float f) {
  union { float f; uint32_t i; } v; v.f = f;
  uint32_t r = (v.i + 0x7FFFu + ((v.i >> 16) & 1u)) >> 16;
  return (u16)r;
}
__device__ __forceinline__ uint4 pack8(const float* sp) {
  float4 f0 = *(const float4*)(sp);
  float4 f1 = *(const float4*)(sp + 4);
  uint4 v;
  v.x = (uint32_t)f2bf(f0.x) | ((uint32_t)f2bf(f0.y) << 16);
  v.y = (uint32_t)f2bf(f0.z) | ((uint32_t)f2bf(f0.w) << 16);
  v.z = (uint32_t)f2bf(f1.x) | ((uint32_t)f2bf(f1.y) << 16);
  v.w = (uint32_t)f2bf(f1.z) | ((uint32_t)f2bf(f1.w) << 16);
  return v;
}
// mish(x) = x*tanh(softplus(x))
__device__ __forceinline__ float mish_f(float x) {
  float t = __expf(fminf(x, 30.f));
  float u = 1.f + t; u = u * u;
  return x * (u - 1.f) / (u + 1.f);
}

// ---------- normalize indices: auto-detect int64 vs int32, emit int32 ----------
__global__ __launch_bounds__(256) void norm_kernel(
    const int* __restrict__ r0, const int* __restrict__ r1,
    const int* __restrict__ r2, int* __restrict__ n)
{
  int g = blockIdx.x * 256 + (int)threadIdx.x;   // grid covers TOTI exactly
  const int* src; int off;
  if (g < L0R)              { src = r0; off = g; }
  else if (g < L0R + L1R)   { src = r1; off = g - L0R; }
  else                      { src = r2; off = g - L0R - L1R; }
  int lane = (int)threadIdx.x & 63;
  int probe = src[2 * lane + 1];
  bool i64 = (__ballot(probe == 0) == ~0ull);
  n[g] = i64 ? src[2 * off] : src[off];
}

// ---------- prep: fp32 weights -> bf16 W^T ----------
__global__ __launch_bounds__(256) void prep_kernel(
    const float* w0, const float* w1, const float* w2, const float* w3,
    const float* w4, const float* w5, const float* w6, const float* w7,
    u16* __restrict__ wt)
{
  int b = blockIdx.x;
  const float* srcs[8] = {w0, w1, w2, w3, w4, w5, w6, w7};
  const int fi[8]   = {64, 64, 128, 128, 192, 192, 128, 128};
  const int fo[8]   = {64, 64, 128, 128, 192, 192, 128, 64};
  const int boff[9] = {0, 16, 32, 96, 160, 304, 448, 512, 544};
  const int woff[8] = {0, 4096, 8192, 24576, 40960, 77824, 114688, 131072};
  int m = 0;
  #pragma unroll
  for (int j = 0; j < 8; ++j) if (b >= boff[j + 1]) m = j + 1;
  int e = (b - boff[m]) * 256 + (int)threadIdx.x;
  int k = e / fo[m];
  int n = e - k * fo[m];
  wt[woff[m] + n * fi[m] + k] = f2bf(srcs[m][e]);   // wt row n: K-contiguous
}

// ---------- flag objects written by relation 0 ----------
__global__ __launch_bounds__(256) void flag_kernel(
    const int* __restrict__ idx0, unsigned char* __restrict__ flag)
{
  int g = blockIdx.x * 256 + (int)threadIdx.x;   // covers L0R exactly
  flag[idx0[g]] = 1;
}

// ---------- matmul phase: acc[NTOUT tiles] = A(g_lds) * W^T ----------
template<int D, int NTOUT>
__device__ __forceinline__ void matmul_phase(
    const u16* __restrict__ wtsrc, u16* w_lds,
    const bf16x8 (&af)[D / 32], floatx4 (&acc)[D / 16],
    int tid, int q, int i)
{
  constexpr int PITCH = D + 8;
  #pragma unroll
  for (int t = 0; t < NTOUT; ++t) acc[t] = (floatx4)0.f;
  #pragma unroll
  for (int ch = 0; ch < NTOUT / 4; ++ch) {
    __syncthreads();   // protect w_lds against previous readers
    for (int c = tid; c < 64 * (D / 8); c += 256) {
      int nr = c / (D / 8), p = c - nr * (D / 8);
      *(uint4*)(&w_lds[nr * PITCH + p * 8]) =
          *(const uint4*)(wtsrc + (size_t)(ch * 64 + nr) * D + p * 8);
    }
    __syncthreads();
    #pragma unroll
    for (int k = 0; k < D / 32; ++k) {
      #pragma unroll
      for (int nt = 0; nt < 4; ++nt) {
        bf16x8 bf = *(const bf16x8*)(&w_lds[(nt * 16 + i) * PITCH + k * 32 + q * 8]);
        acc[ch * 4 + nt] =
            __builtin_amdgcn_mfma_f32_16x16x32_bf16(af[k], bf, acc[ch * 4 + nt], 0, 0, 0);
      }
    }
  }
}

// ---------- fused gather + 2-layer MLP ----------
// MODE 0: relation kernel; rows gathered via idx from fp32 obj_emb; epilogue
//         scatters atomicAdd(exp(12*y)) into s[obj][col] (ROW-major fp32:
//         16 lanes of a quad hit 16 consecutive floats -> 1-2 lines/row).
// MODE 1: update kernel; rows = [maxmsg(bf16) | obj_emb(fp32)] -> fp32 d_out.
template<int D, int DOUT, int MODE>
__global__ __launch_bounds__(256, (D >= 192) ? 3 : 4) void mlp_kernel(
    const float* __restrict__ srcE, const u16* __restrict__ srcM,
    const int* __restrict__ idx,
    const u16* __restrict__ rwt, const float* __restrict__ rb,
    const u16* __restrict__ owt, const float* __restrict__ ob,
    float* __restrict__ dstF, float* __restrict__ dstS)
{
  constexpr int A = D / 64;
  constexpr int PITCH = D + 8;   // bf16 elems; rows 16B aligned
  constexpr int NT1 = D / 16;
  constexpr int NT2 = DOUT / 16;
  constexpr int KI = D / 32;
  __shared__ alignas(16) u16 g_lds[64 * PITCH];
  __shared__ alignas(16) u16 w_lds[64 * PITCH];
  __shared__ float b1_lds[D];
  __shared__ float b2_lds[DOUT];
  __shared__ int i_lds[64 * A];

  const int tid = threadIdx.x;
  const int wave = tid >> 6;
  const int lane = tid & 63;
  const int q = lane >> 4;
  const int i = lane & 15;
  const int t0 = blockIdx.x * 64;

  for (int c = tid; c < D; c += 256) b1_lds[c] = rb[c];
  for (int c = tid; c < DOUT; c += 256) b2_lds[c] = ob[c];
  if (MODE == 0 && tid < 64 * A) i_lds[tid] = idx[t0 * A + tid];

  // stage G: 64 tuples x A entity-rows x 8 chunks of 8 bf16 (fp32 -> bf16)
  for (int c = tid; c < 64 * A * 8; c += 256) {
    int e = c >> 3, p = c & 7;
    int r = e / A, sl = e - r * A;
    uint4 val;
    if (MODE == 0) {
      int obj = idx[(t0 + r) * A + sl];
      val = pack8(srcE + (size_t)obj * 64 + p * 8);
    } else {
      if (sl == 0) val = *(const uint4*)(srcM + (size_t)(t0 + r) * 64 + p * 8);
      else         val = pack8(srcE + (size_t)(t0 + r) * 64 + p * 8);
    }
    *(uint4*)(&g_lds[r * PITCH + sl * 64 + p * 8]) = val;
  }
  __syncthreads();

  floatx4 acc[NT1];
  bf16x8 af[KI];

  // phase 1: H = G @ RW
  #pragma unroll
  for (int k = 0; k < KI; ++k)
    af[k] = *(const bf16x8*)(&g_lds[(wave * 16 + i) * PITCH + k * 32 + q * 8]);
  matmul_phase<D, NT1>(rwt, w_lds, af, acc, tid, q, i);

  // epilogue 1: a2 = g + mish(h) in place (each wave owns its 16 rows)
  #pragma unroll
  for (int t = 0; t < NT1; ++t) {
    #pragma unroll
    for (int r = 0; r < 4; ++r) {
      int row = wave * 16 + q * 4 + r;
      int col = t * 16 + i;
      float h = acc[t][r] + b1_lds[col];
      float g = bf2f(g_lds[row * PITCH + col]);
      g_lds[row * PITCH + col] = f2bf(g + mish_f(h));
    }
  }

  // phase 2: Y = A2 @ OW
  #pragma unroll
  for (int k = 0; k < KI; ++k)
    af[k] = *(const bf16x8*)(&g_lds[(wave * 16 + i) * PITCH + k * 32 + q * 8]);
  matmul_phase<D, NT2>(owt, w_lds, af, acc, tid, q, i);

  // epilogue 2
  #pragma unroll
  for (int t = 0; t < NT2; ++t) {
    #pragma unroll
    for (int r = 0; r < 4; ++r) {
      int row = wave * 16 + q * 4 + r;
      int col = t * 16 + i;
      float y = acc[t][r] + b2_lds[col];
      if (MODE == 0) {
        int slot = col >> 6, cc = col & 63;
        int obj = i_lds[row * A + slot];
        // ROW-major s: lanes i=0..15 hit consecutive floats of one obj row
        atomicAdd(&dstS[(size_t)obj * 64 + cc], __expf(fminf(12.f * y, 82.f)));
      } else {
        dstF[(size_t)(t0 + row) * 64 + col] = y;
      }
    }
  }
}

// ---------- finalize: maxmsg[o][c] = log(s[o][c] + eps)/12 (bf16 into ws) ----------
__global__ __launch_bounds__(256) void final_kernel(
    const float* __restrict__ s, const unsigned char* __restrict__ flag,
    u16* __restrict__ maxmsg)
{
  int tid = (int)threadIdx.x;
  int o = blockIdx.x * 64 + (tid >> 2);      // 64 objects per block
  int c0 = (tid & 3) * 16;                   // 16 cols per thread
  float add = flag[o] ? 1e-37f : 1e-16f;
  const float* sp = s + (size_t)o * 64 + c0;
  u16* mp = maxmsg + (size_t)o * 64 + c0;
  u16 tmp[16];
  #pragma unroll
  for (int j = 0; j < 16; ++j)
    tmp[j] = f2bf(__logf(sp[j] + add) * (1.f / 12.f));
  *(uint4*)(mp)     = *(uint4*)(tmp);
  *(uint4*)(mp + 8) = *(uint4*)(tmp + 8);
}

extern "C" void kernel_launch(void* const* d_in, const int* in_sizes, int n_in,
                              void* d_out, int out_size, void* d_ws, size_t ws_size,
                              hipStream_t stream)
{
  (void)in_sizes; (void)n_in; (void)out_size; (void)ws_size;
  const float* obj_emb = (const float*)d_in[0];
  const float* r0rb = (const float*)d_in[5];
  const float* r0ob = (const float*)d_in[7];
  const float* r1rb = (const float*)d_in[9];
  const float* r1ob = (const float*)d_in[11];
  const float* r2rb = (const float*)d_in[13];
  const float* r2ob = (const float*)d_in[15];
  const float* urb  = (const float*)d_in[17];
  const float* uob  = (const float*)d_in[19];

  char* ws = (char*)d_ws;
  float* s           = (float*)(ws);
  u16* wt            = (u16*)(ws + 33554432ull);
  unsigned char* flg = (unsigned char*)(ws + 33832960ull);
  u16* maxmsg        = (u16*)(ws + 33964032ull);
  int* nidx          = (int*)(ws + 50741248ull);
  float* out         = (float*)d_out;

  hipMemsetAsync(s, 0, 64ull * N_OBJ * 4ull, stream);
  hipMemsetAsync(flg, 0, N_OBJ, stream);

  norm_kernel<<<TOTI / 256, 256, 0, stream>>>(
      (const int*)d_in[1], (const int*)d_in[2], (const int*)d_in[3], nidx);
  prep_kernel<<<544, 256, 0, stream>>>(
      (const float*)d_in[4], (const float*)d_in[6], (const float*)d_in[8],
      (const float*)d_in[10], (const float*)d_in[12], (const float*)d_in[14],
      (const float*)d_in[16], (const float*)d_in[18], wt);
  flag_kernel<<<L0R / 256, 256, 0, stream>>>(nidx, flg);

  mlp_kernel<64, 64, 0><<<4096, 256, 0, stream>>>(
      obj_emb, nullptr, nidx, wt + 0, r0rb, wt + 4096, r0ob, nullptr, s);
  mlp_kernel<128, 128, 0><<<4096, 256, 0, stream>>>(
      obj_emb, nullptr, nidx + L0R, wt + 8192, r1rb, wt + 24576, r1ob, nullptr, s);
  mlp_kernel<192, 192, 0><<<2048, 256, 0, stream>>>(
      obj_emb, nullptr, nidx + L0R + L1R, wt + 40960, r2rb, wt + 77824, r2ob, nullptr, s);

  final_kernel<<<N_OBJ / 64, 256, 0, stream>>>(s, flg, maxmsg);

  mlp_kernel<128, 64, 1><<<2048, 256, 0, stream>>>(
      obj_emb, maxmsg, nullptr, wt + 114688, urb, wt + 131072, uob, out, nullptr);
}

// Round 5
// 480.318 us; speedup vs baseline: 7.8502x; 1.0043x over previous
//
#include <hip/hip_runtime.h>
#include <stdint.h>

typedef unsigned short u16;
typedef __bf16 bf16x8 __attribute__((ext_vector_type(8)));
typedef float floatx4 __attribute__((ext_vector_type(4)));

#define N_OBJ    131072
#define L0R      262144
#define L1R      524288
#define L2R      393216
#define TOTI     (L0R + L1R + L2R)   // 1179648

// ---- workspace layout (bytes), total ~38.7 MB ----
// s      bf16 [N][64] ROW-major   @ 0          (16,777,216)
// wt     bf16 transposed weights  @ 16777216   (278,528)
// flag   u8   [N] written-by-rel0 @ 17055744   (131,072)
// maxmsg bf16 [N][64]             @ 17186816   (16,777,216)
// nidx   i32  [TOTI] normalized   @ 33964032   (4,718,592)

__device__ __forceinline__ float bf2f(u16 u) {
  union { uint32_t i; float f; } v; v.i = ((uint32_t)u) << 16; return v.f;
}
__device__ __forceinline__ u16 f2bf(float f) {
  union { float f; uint32_t i; } v; v.f = f;
  uint32_t r = (v.i + 0x7FFFu + ((v.i >> 16) & 1u)) >> 16;
  return (u16)r;
}
__device__ __forceinline__ uint4 pack8(const float* sp) {
  float4 f0 = *(const float4*)(sp);
  float4 f1 = *(const float4*)(sp + 4);
  uint4 v;
  v.x = (uint32_t)f2bf(f0.x) | ((uint32_t)f2bf(f0.y) << 16);
  v.y = (uint32_t)f2bf(f0.z) | ((uint32_t)f2bf(f0.w) << 16);
  v.z = (uint32_t)f2bf(f1.x) | ((uint32_t)f2bf(f1.y) << 16);
  v.w = (uint32_t)f2bf(f1.z) | ((uint32_t)f2bf(f1.w) << 16);
  return v;
}
// mish(x) = x*tanh(softplus(x))
__device__ __forceinline__ float mish_f(float x) {
  float t = __expf(fminf(x, 30.f));
  float u = 1.f + t; u = u * u;
  return x * (u - 1.f) / (u + 1.f);
}

// ---------- normalize indices: auto-detect int64 vs int32, emit int32 ----------
__global__ __launch_bounds__(256) void norm_kernel(
    const int* __restrict__ r0, const int* __restrict__ r1,
    const int* __restrict__ r2, int* __restrict__ n)
{
  int g = blockIdx.x * 256 + (int)threadIdx.x;   // grid covers TOTI exactly
  const int* src; int off;
  if (g < L0R)              { src = r0; off = g; }
  else if (g < L0R + L1R)   { src = r1; off = g - L0R; }
  else                      { src = r2; off = g - L0R - L1R; }
  int lane = (int)threadIdx.x & 63;
  int probe = src[2 * lane + 1];
  bool i64 = (__ballot(probe == 0) == ~0ull);
  n[g] = i64 ? src[2 * off] : src[off];
}

// ---------- prep: fp32 weights -> bf16 W^T ----------
__global__ __launch_bounds__(256) void prep_kernel(
    const float* w0, const float* w1, const float* w2, const float* w3,
    const float* w4, const float* w5, const float* w6, const float* w7,
    u16* __restrict__ wt)
{
  int b = blockIdx.x;
  const float* srcs[8] = {w0, w1, w2, w3, w4, w5, w6, w7};
  const int fi[8]   = {64, 64, 128, 128, 192, 192, 128, 128};
  const int fo[8]   = {64, 64, 128, 128, 192, 192, 128, 64};
  const int boff[9] = {0, 16, 32, 96, 160, 304, 448, 512, 544};
  const int woff[8] = {0, 4096, 8192, 24576, 40960, 77824, 114688, 131072};
  int m = 0;
  #pragma unroll
  for (int j = 0; j < 8; ++j) if (b >= boff[j + 1]) m = j + 1;
  int e = (b - boff[m]) * 256 + (int)threadIdx.x;
  int k = e / fo[m];
  int n = e - k * fo[m];
  wt[woff[m] + n * fi[m] + k] = f2bf(srcs[m][e]);   // wt row n: K-contiguous
}

// ---------- flag objects written by relation 0 ----------
__global__ __launch_bounds__(256) void flag_kernel(
    const int* __restrict__ idx0, unsigned char* __restrict__ flag)
{
  int g = blockIdx.x * 256 + (int)threadIdx.x;   // covers L0R exactly
  flag[idx0[g]] = 1;
}

// ---------- matmul phase: acc[NTOUT tiles] = A(g_lds) * W^T ----------
template<int D, int NTOUT>
__device__ __forceinline__ void matmul_phase(
    const u16* __restrict__ wtsrc, u16* w_lds,
    const bf16x8 (&af)[D / 32], floatx4 (&acc)[D / 16],
    int tid, int q, int i)
{
  constexpr int PITCH = D + 8;
  #pragma unroll
  for (int t = 0; t < NTOUT; ++t) acc[t] = (floatx4)0.f;
  #pragma unroll
  for (int ch = 0; ch < NTOUT / 4; ++ch) {
    __syncthreads();   // protect w_lds against previous readers
    for (int c = tid; c < 64 * (D / 8); c += 256) {
      int nr = c / (D / 8), p = c - nr * (D / 8);
      *(uint4*)(&w_lds[nr * PITCH + p * 8]) =
          *(const uint4*)(wtsrc + (size_t)(ch * 64 + nr) * D + p * 8);
    }
    __syncthreads();
    #pragma unroll
    for (int k = 0; k < D / 32; ++k) {
      #pragma unroll
      for (int nt = 0; nt < 4; ++nt) {
        bf16x8 bf = *(const bf16x8*)(&w_lds[(nt * 16 + i) * PITCH + k * 32 + q * 8]);
        acc[ch * 4 + nt] =
            __builtin_amdgcn_mfma_f32_16x16x32_bf16(af[k], bf, acc[ch * 4 + nt], 0, 0, 0);
      }
    }
  }
}

// ---------- fused gather + 2-layer MLP ----------
// MODE 0: relation kernel; rows gathered via idx from fp32 obj_emb; epilogue
//         scatters packed-bf16 atomic adds of exp(12*y) into s[obj][col]
//         (row-major; lane pairs (i,i+1) pack adjacent cols into one dword:
//         halves atomic dword count AND atomic write traffic vs fp32).
// MODE 1: update kernel; rows = [maxmsg(bf16) | obj_emb(fp32)] -> fp32 d_out.
template<int D, int DOUT, int MODE>
__global__ __launch_bounds__(256, (D >= 192) ? 3 : 4) void mlp_kernel(
    const float* __restrict__ srcE, const u16* __restrict__ srcM,
    const int* __restrict__ idx,
    const u16* __restrict__ rwt, const float* __restrict__ rb,
    const u16* __restrict__ owt, const float* __restrict__ ob,
    float* __restrict__ dstF, u16* __restrict__ dstS)
{
  constexpr int A = D / 64;
  constexpr int PITCH = D + 8;   // bf16 elems; rows 16B aligned
  constexpr int NT1 = D / 16;
  constexpr int NT2 = DOUT / 16;
  constexpr int KI = D / 32;
  __shared__ alignas(16) u16 g_lds[64 * PITCH];
  __shared__ alignas(16) u16 w_lds[64 * PITCH];
  __shared__ float b1_lds[D];
  __shared__ float b2_lds[DOUT];
  __shared__ int i_lds[64 * A];

  const int tid = threadIdx.x;
  const int wave = tid >> 6;
  const int lane = tid & 63;
  const int q = lane >> 4;
  const int i = lane & 15;
  const int t0 = blockIdx.x * 64;

  for (int c = tid; c < D; c += 256) b1_lds[c] = rb[c];
  for (int c = tid; c < DOUT; c += 256) b2_lds[c] = ob[c];
  if (MODE == 0 && tid < 64 * A) i_lds[tid] = idx[t0 * A + tid];

  // stage G: 64 tuples x A entity-rows x 8 chunks of 8 bf16 (fp32 -> bf16)
  for (int c = tid; c < 64 * A * 8; c += 256) {
    int e = c >> 3, p = c & 7;
    int r = e / A, sl = e - r * A;
    uint4 val;
    if (MODE == 0) {
      int obj = idx[(t0 + r) * A + sl];
      val = pack8(srcE + (size_t)obj * 64 + p * 8);
    } else {
      if (sl == 0) val = *(const uint4*)(srcM + (size_t)(t0 + r) * 64 + p * 8);
      else         val = pack8(srcE + (size_t)(t0 + r) * 64 + p * 8);
    }
    *(uint4*)(&g_lds[r * PITCH + sl * 64 + p * 8]) = val;
  }
  __syncthreads();

  floatx4 acc[NT1];
  bf16x8 af[KI];

  // phase 1: H = G @ RW
  #pragma unroll
  for (int k = 0; k < KI; ++k)
    af[k] = *(const bf16x8*)(&g_lds[(wave * 16 + i) * PITCH + k * 32 + q * 8]);
  matmul_phase<D, NT1>(rwt, w_lds, af, acc, tid, q, i);

  // epilogue 1: a2 = g + mish(h) in place (each wave owns its 16 rows)
  #pragma unroll
  for (int t = 0; t < NT1; ++t) {
    #pragma unroll
    for (int r = 0; r < 4; ++r) {
      int row = wave * 16 + q * 4 + r;
      int col = t * 16 + i;
      float h = acc[t][r] + b1_lds[col];
      float g = bf2f(g_lds[row * PITCH + col]);
      g_lds[row * PITCH + col] = f2bf(g + mish_f(h));
    }
  }

  // phase 2: Y = A2 @ OW
  #pragma unroll
  for (int k = 0; k < KI; ++k)
    af[k] = *(const bf16x8*)(&g_lds[(wave * 16 + i) * PITCH + k * 32 + q * 8]);
  matmul_phase<D, NT2>(owt, w_lds, af, acc, tid, q, i);

  // epilogue 2
  if (MODE == 0) {
    #pragma unroll
    for (int t = 0; t < NT2; ++t) {
      int col = t * 16 + i;
      int slot = col >> 6, cc = col & 63;
      float e[4], p[4];
      #pragma unroll
      for (int r = 0; r < 4; ++r)
        e[r] = __expf(fminf(12.f * (acc[t][r] + b2_lds[col]), 82.f));
      #pragma unroll
      for (int r = 0; r < 4; ++r) p[r] = __shfl_xor(e[r], 1);
      if ((i & 1) == 0) {   // even lane packs (own col, col+1): same row, same obj
        #pragma unroll
        for (int r = 0; r < 4; ++r) {
          int row = wave * 16 + q * 4 + r;
          int obj = i_lds[row * A + slot];
          uint32_t packed = (uint32_t)f2bf(e[r]) | ((uint32_t)f2bf(p[r]) << 16);
          u16* addr = dstS + (size_t)obj * 64 + cc;
          asm volatile("global_atomic_pk_add_bf16 %0, %1, off"
                       :: "v"(addr), "v"(packed) : "memory");
        }
      }
    }
    // ensure atomics are visible before dispatch end (asm bypasses compiler's
    // outstanding-op tracking)
    asm volatile("s_waitcnt vmcnt(0)" ::: "memory");
  } else {
    #pragma unroll
    for (int t = 0; t < NT2; ++t) {
      #pragma unroll
      for (int r = 0; r < 4; ++r) {
        int row = wave * 16 + q * 4 + r;
        int col = t * 16 + i;
        dstF[(size_t)(t0 + row) * 64 + col] = acc[t][r] + b2_lds[col];
      }
    }
  }
}

// ---------- finalize: maxmsg[o][c] = log(s[o][c] + eps)/12 (bf16 into ws) ----------
__global__ __launch_bounds__(256) void final_kernel(
    const u16* __restrict__ s, const unsigned char* __restrict__ flag,
    u16* __restrict__ maxmsg)
{
  int tid = (int)threadIdx.x;
  int o = blockIdx.x * 64 + (tid >> 2);      // 64 objects per block
  int c0 = (tid & 3) * 16;                   // 16 cols per thread
  float add = flag[o] ? 1e-37f : 1e-16f;
  const u16* sp = s + (size_t)o * 64 + c0;
  u16* mp = maxmsg + (size_t)o * 64 + c0;
  union { uint4 v; u16 a[8]; } in0, in1;
  in0.v = *(const uint4*)(sp);
  in1.v = *(const uint4*)(sp + 8);
  u16 tmp[16];
  #pragma unroll
  for (int j = 0; j < 8; ++j)
    tmp[j] = f2bf(__logf(bf2f(in0.a[j]) + add) * (1.f / 12.f));
  #pragma unroll
  for (int j = 0; j < 8; ++j)
    tmp[8 + j] = f2bf(__logf(bf2f(in1.a[j]) + add) * (1.f / 12.f));
  *(uint4*)(mp)     = *(uint4*)(tmp);
  *(uint4*)(mp + 8) = *(uint4*)(tmp + 8);
}

extern "C" void kernel_launch(void* const* d_in, const int* in_sizes, int n_in,
                              void* d_out, int out_size, void* d_ws, size_t ws_size,
                              hipStream_t stream)
{
  (void)in_sizes; (void)n_in; (void)out_size; (void)ws_size;
  const float* obj_emb = (const float*)d_in[0];
  const float* r0rb = (const float*)d_in[5];
  const float* r0ob = (const float*)d_in[7];
  const float* r1rb = (const float*)d_in[9];
  const float* r1ob = (const float*)d_in[11];
  const float* r2rb = (const float*)d_in[13];
  const float* r2ob = (const float*)d_in[15];
  const float* urb  = (const float*)d_in[17];
  const float* uob  = (const float*)d_in[19];

  char* ws = (char*)d_ws;
  u16* s             = (u16*)(ws);
  u16* wt            = (u16*)(ws + 16777216ull);
  unsigned char* flg = (unsigned char*)(ws + 17055744ull);
  u16* maxmsg        = (u16*)(ws + 17186816ull);
  int* nidx          = (int*)(ws + 33964032ull);
  float* out         = (float*)d_out;

  hipMemsetAsync(s, 0, 64ull * N_OBJ * 2ull, stream);
  hipMemsetAsync(flg, 0, N_OBJ, stream);

  norm_kernel<<<TOTI / 256, 256, 0, stream>>>(
      (const int*)d_in[1], (const int*)d_in[2], (const int*)d_in[3], nidx);
  prep_kernel<<<544, 256, 0, stream>>>(
      (const float*)d_in[4], (const float*)d_in[6], (const float*)d_in[8],
      (const float*)d_in[10], (const float*)d_in[12], (const float*)d_in[14],
      (const float*)d_in[16], (const float*)d_in[18], wt);
  flag_kernel<<<L0R / 256, 256, 0, stream>>>(nidx, flg);

  mlp_kernel<64, 64, 0><<<4096, 256, 0, stream>>>(
      obj_emb, nullptr, nidx, wt + 0, r0rb, wt + 4096, r0ob, nullptr, s);
  mlp_kernel<128, 128, 0><<<4096, 256, 0, stream>>>(
      obj_emb, nullptr, nidx + L0R, wt + 8192, r1rb, wt + 24576, r1ob, nullptr, s);
  mlp_kernel<192, 192, 0><<<2048, 256, 0, stream>>>(
      obj_emb, nullptr, nidx + L0R + L1R, wt + 40960, r2rb, wt + 77824, r2ob, nullptr, s);

  final_kernel<<<N_OBJ / 64, 256, 0, stream>>>(s, flg, maxmsg);

  mlp_kernel<128, 64, 1><<<2048, 256, 0, stream>>>(
      obj_emb, maxmsg, nullptr, wt + 114688, urb, wt + 131072, uob, out, nullptr);
}